// Round 14
// baseline (82.346 us; speedup 1.0000x reference)
//
#include <hip/hip_runtime.h>

// MPS periodic chain: psi_b = tr( prod_{i=0..63} (param[i][x[b,i]] + I) )
// d_out: float32[4096], out[b] = log|psi_b|.
//
// Round-13 lesson: P8 table (18 MB) >> per-XCD L2 (4 MB) -> chain was L2-miss
// bound (FETCH 97 MB, ~1.5 TB/s effective); depth-splitting was neutral.
// Fix: P4 table = 16 segments x 16 combos x 8 KB = 2.1 MB -> L2-RESIDENT.
// Chain: 14 shuffle-multiplies (pipe-bound, cheap) instead of 6 miss-bound ones.
//
//  prep:      T = param + I -> bf16 (Tn row-major, Tt transposed)
//  build_p4:  256 waves; wave (s,c) computes P4[s][c] = prod_{j=0..3} T[4s+j][bit_{3-j}(c)]
//             right-to-left in registers. Stores P4n (all s), P4t (s==15 only).
//  chain:     one wave per batch: E := P4t[15][i15]; for s=14..1: E := P4n[s][is]*E;
//             psi = tr(P4n[0][i0]*E) via diagonal tiles; out[b] = log|psi|.
//
// MFMA v_mfma_f32_16x16x32_bf16 layouts (verified rounds 9/11/12):
//  A: lane l holds X[m=(l&15)+16mi][k=8*(l>>4)+32ks+j], j=0..7
//  B: lane l holds Y[k=8*(l>>4)+32ks+j][n=(l&15)+16nj]
//  D: lane l reg r holds C[m=4*(l>>4)+r+16mi][n=(l&15)+16nj]
// D->B (verified): dest lane (p',c) word w of B[ks][nj] =
//  pk[mi=2ks+(p'>>1)][nj][h=w&1] from src lane c+32*(p'&1)+16*(w>>1);
//  ALL shuffles convergent (whole wave active), select after.

typedef __attribute__((ext_vector_type(8))) __bf16 bf16x8;
typedef __attribute__((ext_vector_type(4))) float f32x4;
typedef __attribute__((ext_vector_type(4))) int   int4v;

#define MFMA16(a, b, c) __builtin_amdgcn_mfma_f32_16x16x32_bf16((a), (b), (c), 0, 0, 0)

union frag_u { int4v i; bf16x8 v; };

__device__ __forceinline__ unsigned short f2bf(float f) {
  union { float f; unsigned u; } v; v.f = f;
  unsigned r = v.u + 0x7fffu + ((v.u >> 16) & 1u);   // RNE
  return (unsigned short)(r >> 16);
}

// ---------------- phase 0: param + I -> bf16, normal + transposed ----------------
__global__ __launch_bounds__(256) void prep_kernel(const float* __restrict__ p,
                                                   unsigned short* __restrict__ Tn,
                                                   unsigned short* __restrict__ Tt) {
  int t = blockIdx.x * 256 + threadIdx.x;      // 0 .. 524287
  int j  = t & 63;
  int i  = (t >> 6) & 63;
  int pq = t >> 12;                            // [site][digit] 0..127
  float v = p[t] + ((i == j) ? 1.0f : 0.0f);
  unsigned short h = f2bf(v);
  Tn[t] = h;
  Tt[(((size_t)pq) << 12) + (size_t)j * 64 + i] = h;
}

// ---------------- phase 1: P4 table, one wave per (segment, combo) ----------------
__global__ __launch_bounds__(256) void build_p4_kernel(const unsigned short* __restrict__ Tn,
                                                       const unsigned short* __restrict__ Tt,
                                                       unsigned short* __restrict__ P4n,
                                                       unsigned short* __restrict__ P4t) {
  const int tid = threadIdx.x;
  const int l   = tid & 63;
  const int w   = blockIdx.x * 4 + (tid >> 6);   // 0..255
  const int s   = w >> 4, cmb = w & 15;          // segment (4 sites), combo (site 4s = MSB)
  const int c   = l & 15, p = l >> 4;

  const int srcA = (l & 15) | ((l & 16) << 1);
  const int srcB = srcA | 16;
  const bool hi5 = (l & 32) != 0;

  // B := T[site 4s+3] as B-frags from Tt
  frag_u B[2][4];
  {
    int m3 = (4 * s + 3) * 2 + (cmb & 1);
    const unsigned short* base = Tt + ((size_t)m3 << 12);
#pragma unroll
    for (int ks = 0; ks < 2; ++ks)
#pragma unroll
      for (int nj = 0; nj < 4; ++nj)
        B[ks][nj].i = *reinterpret_cast<const int4v*>(base + (c + 16 * nj) * 64 + 32 * ks + 8 * p);
  }

  // sites j = 2, 1 : B := T[4s+j][digit] * B
#pragma unroll
  for (int j = 2; j >= 1; --j) {
    int m = (4 * s + j) * 2 + ((cmb >> (3 - j)) & 1);
    const unsigned short* abase = Tn + ((size_t)m << 12);
    frag_u A[4][2];
#pragma unroll
    for (int mi = 0; mi < 4; ++mi)
#pragma unroll
      for (int ks = 0; ks < 2; ++ks)
        A[mi][ks].i = *reinterpret_cast<const int4v*>(abase + (c + 16 * mi) * 64 + 32 * ks + 8 * p);

    int pk[4][4][2];
#pragma unroll
    for (int mi = 0; mi < 4; ++mi)
#pragma unroll
      for (int nj = 0; nj < 4; ++nj) {
        f32x4 d = {0.f, 0.f, 0.f, 0.f};
        d = MFMA16(A[mi][0].v, B[0][nj].v, d);
        d = MFMA16(A[mi][1].v, B[1][nj].v, d);
        asm("v_cvt_pk_bf16_f32 %0, %1, %2" : "=v"(pk[mi][nj][0]) : "v"(d[0]), "v"(d[1]));
        asm("v_cvt_pk_bf16_f32 %0, %1, %2" : "=v"(pk[mi][nj][1]) : "v"(d[2]), "v"(d[3]));
      }
#pragma unroll
    for (int ks = 0; ks < 2; ++ks)
#pragma unroll
      for (int nj = 0; nj < 4; ++nj) {
        int lo0 = pk[2 * ks][nj][0],     lo1 = pk[2 * ks][nj][1];
        int hi0 = pk[2 * ks + 1][nj][0], hi1 = pk[2 * ks + 1][nj][1];
        int a0 = __shfl(lo0, srcA, 64), b0 = __shfl(hi0, srcA, 64);
        int a1 = __shfl(lo1, srcA, 64), b1 = __shfl(hi1, srcA, 64);
        int a2 = __shfl(lo0, srcB, 64), b2 = __shfl(hi0, srcB, 64);
        int a3 = __shfl(lo1, srcB, 64), b3 = __shfl(hi1, srcB, 64);
        int4v nb = { hi5 ? b0 : a0, hi5 ? b1 : a1, hi5 ? b2 : a2, hi5 ? b3 : a3 };
        B[ks][nj].i = nb;
      }
  }

  // final site 4s: full D = A(T) x B; store P4n (all), P4t (s==15)
  {
    int m0 = (4 * s) * 2 + ((cmb >> 3) & 1);
    const unsigned short* abase = Tn + ((size_t)m0 << 12);
    frag_u A[4][2];
#pragma unroll
    for (int mi = 0; mi < 4; ++mi)
#pragma unroll
      for (int ks = 0; ks < 2; ++ks)
        A[mi][ks].i = *reinterpret_cast<const int4v*>(abase + (c + 16 * mi) * 64 + 32 * ks + 8 * p);

    unsigned short* ON = P4n + (((size_t)w) << 12);
    unsigned short* OT = P4t + (((size_t)cmb) << 12);
    const bool wantT = (s == 15);
#pragma unroll
    for (int mi = 0; mi < 4; ++mi)
#pragma unroll
      for (int nj = 0; nj < 4; ++nj) {
        f32x4 d = {0.f, 0.f, 0.f, 0.f};
        d = MFMA16(A[mi][0].v, B[0][nj].v, d);
        d = MFMA16(A[mi][1].v, B[1][nj].v, d);
        // row-major store (A-frag source for chain)
        int row0 = 16 * mi + 4 * p, col = 16 * nj + c;
#pragma unroll
        for (int r = 0; r < 4; ++r)
          ON[(size_t)(row0 + r) * 64 + col] = f2bf(d[r]);
        if (wantT) {   // transposed store (chain's initial B-frags)
          int n = 16 * nj + c, m0r = 16 * mi + 4 * p;
          ushort4 pkv;
          pkv.x = f2bf(d[0]); pkv.y = f2bf(d[1]);
          pkv.z = f2bf(d[2]); pkv.w = f2bf(d[3]);
          *reinterpret_cast<ushort4*>(OT + (size_t)n * 64 + m0r) = pkv;
        }
      }
  }
}

// ---------------- phase 2: register-resident per-wave chain (16 P4 factors) ----------------
__global__ __launch_bounds__(256) void chain_wave_kernel(const int* __restrict__ x,
                                                         const unsigned short* __restrict__ P4n,
                                                         const unsigned short* __restrict__ P4t,
                                                         float* __restrict__ out) {
  const int tid = threadIdx.x;
  const int l   = tid & 63;
  const int b   = blockIdx.x * 4 + (tid >> 6);   // one wave per batch
  const int c   = l & 15;
  const int p   = l >> 4;

  // 16 nibble indices from ballot (leftmost site of segment = MSB)
  unsigned long long mask = __ballot((x[b * 64 + l] & 1) != 0);
  int idx[16];
#pragma unroll
  for (int s = 0; s < 16; ++s) {
    unsigned nib = (unsigned)((mask >> (4 * s)) & 0xFull);
    idx[s] = (int)(__builtin_bitreverse32(nib) >> 28);
  }

  const int srcA = (l & 15) | ((l & 16) << 1);
  const int srcB = srcA | 16;
  const bool hi5 = (l & 32) != 0;

  // E := P4[15][idx15] as B-frags
  frag_u B[2][4];
  {
    const unsigned short* base = P4t + (((size_t)idx[15]) << 12);
#pragma unroll
    for (int ks = 0; ks < 2; ++ks)
#pragma unroll
      for (int nj = 0; nj < 4; ++nj)
        B[ks][nj].i = *reinterpret_cast<const int4v*>(base + (c + 16 * nj) * 64 + 32 * ks + 8 * p);
  }

  // steps s = 14..1 : E := P4[s][idx_s] * E   (all reads L2-resident)
  for (int s = 14; s >= 1; --s) {
    const unsigned short* abase = P4n + (((size_t)(s * 16 + idx[s])) << 12);
    frag_u A[4][2];
#pragma unroll
    for (int mi = 0; mi < 4; ++mi)
#pragma unroll
      for (int ks = 0; ks < 2; ++ks)
        A[mi][ks].i = *reinterpret_cast<const int4v*>(abase + (c + 16 * mi) * 64 + 32 * ks + 8 * p);

    int pk[4][4][2];
#pragma unroll
    for (int mi = 0; mi < 4; ++mi)
#pragma unroll
      for (int nj = 0; nj < 4; ++nj) {
        f32x4 d = {0.f, 0.f, 0.f, 0.f};
        d = MFMA16(A[mi][0].v, B[0][nj].v, d);
        d = MFMA16(A[mi][1].v, B[1][nj].v, d);
        asm("v_cvt_pk_bf16_f32 %0, %1, %2" : "=v"(pk[mi][nj][0]) : "v"(d[0]), "v"(d[1]));
        asm("v_cvt_pk_bf16_f32 %0, %1, %2" : "=v"(pk[mi][nj][1]) : "v"(d[2]), "v"(d[3]));
      }
#pragma unroll
    for (int ks = 0; ks < 2; ++ks)
#pragma unroll
      for (int nj = 0; nj < 4; ++nj) {
        int lo0 = pk[2 * ks][nj][0],     lo1 = pk[2 * ks][nj][1];
        int hi0 = pk[2 * ks + 1][nj][0], hi1 = pk[2 * ks + 1][nj][1];
        int a0 = __shfl(lo0, srcA, 64), b0 = __shfl(hi0, srcA, 64);
        int a1 = __shfl(lo1, srcA, 64), b1 = __shfl(hi1, srcA, 64);
        int a2 = __shfl(lo0, srcB, 64), b2 = __shfl(hi0, srcB, 64);
        int a3 = __shfl(lo1, srcB, 64), b3 = __shfl(hi1, srcB, 64);
        int4v nb = { hi5 ? b0 : a0, hi5 ? b1 : a1, hi5 ? b2 : a2, hi5 ? b3 : a3 };
        B[ks][nj].i = nb;
      }
  }

  // psi = tr(P4[0][idx0] * E): diagonal 16x16 tiles only
  float psum = 0.f;
  {
    const unsigned short* abase = P4n + (((size_t)idx[0]) << 12);
#pragma unroll
    for (int t = 0; t < 4; ++t) {
      frag_u A0, A1;
      A0.i = *reinterpret_cast<const int4v*>(abase + (c + 16 * t) * 64 + 0  + 8 * p);
      A1.i = *reinterpret_cast<const int4v*>(abase + (c + 16 * t) * 64 + 32 + 8 * p);
      f32x4 d = {0.f, 0.f, 0.f, 0.f};
      d = MFMA16(A0.v, B[0][t].v, d);
      d = MFMA16(A1.v, B[1][t].v, d);
      if (p == (c >> 2)) {
#pragma unroll
        for (int r = 0; r < 4; ++r) psum += (r == (c & 3)) ? d[r] : 0.f;
      }
    }
  }
#pragma unroll
  for (int o = 32; o > 0; o >>= 1) psum += __shfl_down(psum, o, 64);
  if (l == 0) out[b] = logf(fabsf(psum));
}

// ---------------- launch ----------------
extern "C" void kernel_launch(void* const* d_in, const int* in_sizes, int n_in,
                              void* d_out, int out_size, void* d_ws, size_t ws_size,
                              hipStream_t stream) {
  const int*   x     = (const int*)d_in[0];     // [4096][64] int32
  const float* param = (const float*)d_in[1];   // [64][2][64][64] f32
  float* out = (float*)d_out;                   // 4096 floats: log|psi_b|

  char* ws = (char*)d_ws;
  unsigned short* Tn  = (unsigned short*)(ws + (0ull << 20));   // 1 MB
  unsigned short* Tt  = (unsigned short*)(ws + (1ull << 20));   // 1 MB
  unsigned short* P4n = (unsigned short*)(ws + (2ull << 20));   // 2 MB (256 x 8 KB)
  unsigned short* P4t = (unsigned short*)(ws + (4ull << 20));   // 128 KB (16 x 8 KB)

  prep_kernel<<<2048, 256, 0, stream>>>(param, Tn, Tt);
  build_p4_kernel<<<64, 256, 0, stream>>>(Tn, Tt, P4n, P4t);
  chain_wave_kernel<<<1024, 256, 0, stream>>>(x, P4n, P4t, out);
}

// Round 15
// 78.811 us; speedup vs baseline: 1.0449x; 1.0449x over previous
//
#include <hip/hip_runtime.h>

// MPS periodic chain: psi_b = tr( prod_{i=0..63} (param[i][x[b,i]] + I) )
// d_out: float32[4096], out[b] = log|psi_b|.
//
// Round-14 lesson: ds_bpermute D->B conversion made the chain DS-pipe-bound
// (7.3M bank-conflict cycles, 64 DS ops/step, MFMA 17%/VALU 25% both idle).
// Fix: chain on v_mfma_f32_32x32x16_bf16. Its D layout (row=(r&3)+8(r>>2)+4*l5,
// col=l&31) and B layout (k=8*l5+j, n=l&31) share lane bits 0-4 -> D->B moves
// data only across lane bit 5 = v_permlane32_swap_b32 (VALU). Zero DS ops.
//
//  prep:      T = param + I -> bf16 (Tn row-major, Tt transposed)
//  build_p4:  256 waves (16x16 path, verified rounds 9-14): P4[s][c], s<16, c<16
//             stores P4n row-major (all s) + P4t transposed (s==15)
//  chain32:   one wave per batch: E := P4t[15][i15] as 32x32 B-frags;
//             for s=14..1: E := P4n[s][is]*E  (16 MFMA32 + 32 cvt_pk + 16 permlane);
//             psi = per-lane dot of P4n[0][i0] A-frags with E B-frags; out=log|psi|.
//
// 32x32x16 layouts: A: lane l holds X[m=l&31][k=8*(l>>5)+j]; B: Y[k=8*(l>>5)+j][n=l&31];
// D: lane l reg r holds C[row=(r&3)+8*(r>>2)+4*(l>>5)][col=l&31] [guide m74/m101].
// D->B: dest (l5',c) word w of B[q][nj] = cvt_pk(d[r0],d[r0+1]), r0=(2w&3)+8(q&1)+4*l5',
// from src half (w>>1); permlane32_swap(P_a,P_b) yields words w and w+2 at once.

typedef __attribute__((ext_vector_type(8)))  __bf16 bf16x8;
typedef __attribute__((ext_vector_type(4)))  float  f32x4;
typedef __attribute__((ext_vector_type(16))) float  f32x16;
typedef __attribute__((ext_vector_type(4)))  int    int4v;

#define MFMA16(a, b, c) __builtin_amdgcn_mfma_f32_16x16x32_bf16((a), (b), (c), 0, 0, 0)
#define MFMA32(a, b, c) __builtin_amdgcn_mfma_f32_32x32x16_bf16((a), (b), (c), 0, 0, 0)

union frag_u { int4v i; bf16x8 v; };

__device__ __forceinline__ unsigned short f2bf(float f) {
  union { float f; unsigned u; } v; v.f = f;
  unsigned r = v.u + 0x7fffu + ((v.u >> 16) & 1u);   // RNE
  return (unsigned short)(r >> 16);
}

// ---------------- phase 0: param + I -> bf16, normal + transposed ----------------
__global__ __launch_bounds__(256) void prep_kernel(const float* __restrict__ p,
                                                   unsigned short* __restrict__ Tn,
                                                   unsigned short* __restrict__ Tt) {
  int t = blockIdx.x * 256 + threadIdx.x;      // 0 .. 524287
  int j  = t & 63;
  int i  = (t >> 6) & 63;
  int pq = t >> 12;                            // [site][digit] 0..127
  float v = p[t] + ((i == j) ? 1.0f : 0.0f);
  unsigned short h = f2bf(v);
  Tn[t] = h;
  Tt[(((size_t)pq) << 12) + (size_t)j * 64 + i] = h;
}

// ---------------- phase 1: P4 table (verified 16x16 + bpermute path) ----------------
__global__ __launch_bounds__(256) void build_p4_kernel(const unsigned short* __restrict__ Tn,
                                                       const unsigned short* __restrict__ Tt,
                                                       unsigned short* __restrict__ P4n,
                                                       unsigned short* __restrict__ P4t) {
  const int tid = threadIdx.x;
  const int l   = tid & 63;
  const int w   = blockIdx.x * 4 + (tid >> 6);   // 0..255
  const int s   = w >> 4, cmb = w & 15;          // segment (4 sites), combo (site 4s = MSB)
  const int c   = l & 15, p = l >> 4;

  const int srcA = (l & 15) | ((l & 16) << 1);
  const int srcB = srcA | 16;
  const bool hi5 = (l & 32) != 0;

  frag_u B[2][4];
  {
    int m3 = (4 * s + 3) * 2 + (cmb & 1);
    const unsigned short* base = Tt + ((size_t)m3 << 12);
#pragma unroll
    for (int ks = 0; ks < 2; ++ks)
#pragma unroll
      for (int nj = 0; nj < 4; ++nj)
        B[ks][nj].i = *reinterpret_cast<const int4v*>(base + (c + 16 * nj) * 64 + 32 * ks + 8 * p);
  }

#pragma unroll
  for (int j = 2; j >= 1; --j) {
    int m = (4 * s + j) * 2 + ((cmb >> (3 - j)) & 1);
    const unsigned short* abase = Tn + ((size_t)m << 12);
    frag_u A[4][2];
#pragma unroll
    for (int mi = 0; mi < 4; ++mi)
#pragma unroll
      for (int ks = 0; ks < 2; ++ks)
        A[mi][ks].i = *reinterpret_cast<const int4v*>(abase + (c + 16 * mi) * 64 + 32 * ks + 8 * p);

    int pk[4][4][2];
#pragma unroll
    for (int mi = 0; mi < 4; ++mi)
#pragma unroll
      for (int nj = 0; nj < 4; ++nj) {
        f32x4 d = {0.f, 0.f, 0.f, 0.f};
        d = MFMA16(A[mi][0].v, B[0][nj].v, d);
        d = MFMA16(A[mi][1].v, B[1][nj].v, d);
        asm("v_cvt_pk_bf16_f32 %0, %1, %2" : "=v"(pk[mi][nj][0]) : "v"(d[0]), "v"(d[1]));
        asm("v_cvt_pk_bf16_f32 %0, %1, %2" : "=v"(pk[mi][nj][1]) : "v"(d[2]), "v"(d[3]));
      }
#pragma unroll
    for (int ks = 0; ks < 2; ++ks)
#pragma unroll
      for (int nj = 0; nj < 4; ++nj) {
        int lo0 = pk[2 * ks][nj][0],     lo1 = pk[2 * ks][nj][1];
        int hi0 = pk[2 * ks + 1][nj][0], hi1 = pk[2 * ks + 1][nj][1];
        int a0 = __shfl(lo0, srcA, 64), b0 = __shfl(hi0, srcA, 64);
        int a1 = __shfl(lo1, srcA, 64), b1 = __shfl(hi1, srcA, 64);
        int a2 = __shfl(lo0, srcB, 64), b2 = __shfl(hi0, srcB, 64);
        int a3 = __shfl(lo1, srcB, 64), b3 = __shfl(hi1, srcB, 64);
        int4v nb = { hi5 ? b0 : a0, hi5 ? b1 : a1, hi5 ? b2 : a2, hi5 ? b3 : a3 };
        B[ks][nj].i = nb;
      }
  }

  {
    int m0 = (4 * s) * 2 + ((cmb >> 3) & 1);
    const unsigned short* abase = Tn + ((size_t)m0 << 12);
    frag_u A[4][2];
#pragma unroll
    for (int mi = 0; mi < 4; ++mi)
#pragma unroll
      for (int ks = 0; ks < 2; ++ks)
        A[mi][ks].i = *reinterpret_cast<const int4v*>(abase + (c + 16 * mi) * 64 + 32 * ks + 8 * p);

    unsigned short* ON = P4n + (((size_t)w) << 12);
    unsigned short* OT = P4t + (((size_t)cmb) << 12);
    const bool wantT = (s == 15);
#pragma unroll
    for (int mi = 0; mi < 4; ++mi)
#pragma unroll
      for (int nj = 0; nj < 4; ++nj) {
        f32x4 d = {0.f, 0.f, 0.f, 0.f};
        d = MFMA16(A[mi][0].v, B[0][nj].v, d);
        d = MFMA16(A[mi][1].v, B[1][nj].v, d);
        int row0 = 16 * mi + 4 * p, col = 16 * nj + c;
#pragma unroll
        for (int r = 0; r < 4; ++r)
          ON[(size_t)(row0 + r) * 64 + col] = f2bf(d[r]);
        if (wantT) {
          int n = 16 * nj + c, m0r = 16 * mi + 4 * p;
          ushort4 pkv;
          pkv.x = f2bf(d[0]); pkv.y = f2bf(d[1]);
          pkv.z = f2bf(d[2]); pkv.w = f2bf(d[3]);
          *reinterpret_cast<ushort4*>(OT + (size_t)n * 64 + m0r) = pkv;
        }
      }
  }
}

// ---------------- phase 2: 32x32 register chain, permlane D->B, no DS ----------------
__global__ __launch_bounds__(256) void chain_wave32_kernel(const int* __restrict__ x,
                                                           const unsigned short* __restrict__ P4n,
                                                           const unsigned short* __restrict__ P4t,
                                                           float* __restrict__ out) {
  const int tid = threadIdx.x;
  const int l   = tid & 63;
  const int b   = blockIdx.x * 4 + (tid >> 6);   // one wave per batch
  const int c5  = l & 31;
  const int l5  = l >> 5;

  // wave-uniform bit mask of this batch's digits
  unsigned long long mask = __ballot((x[b * 64 + l] & 1) != 0);

  // per-lane element offsets (u16 units): t = row/col 32-block, q = 16-wide k-block
  int off[2][4];
#pragma unroll
  for (int t = 0; t < 2; ++t)
#pragma unroll
    for (int q = 0; q < 4; ++q)
      off[t][q] = (32 * t + c5) * 64 + 16 * q + 8 * l5;

  // segment index from the 4-bit nibble (leftmost site = MSB); scalar ops only
  auto segidx = [&](int s) -> int {
    unsigned nib = (unsigned)((mask >> (4 * s)) & 0xFull);
    return (int)(((nib & 1u) << 3) | ((nib & 2u) << 1) | ((nib & 4u) >> 1) | ((nib & 8u) >> 3));
  };

  // E := P4[15][idx15] as 32x32 B-frags: B[q][nj], lane: Y[16q+8*l5+j][32nj+c5]
  int4v B[4][2];
  {
    const unsigned short* base = P4t + (((size_t)segidx(15)) << 12);
#pragma unroll
    for (int q = 0; q < 4; ++q)
#pragma unroll
      for (int nj = 0; nj < 2; ++nj)
        B[q][nj] = *reinterpret_cast<const int4v*>(base + off[nj][q]);
  }

  // steps s = 14..1 : E := P4[s][idx_s] * E   (L2-resident A reads)
#pragma unroll 1
  for (int s = 14; s >= 1; --s) {
    const unsigned short* abase = P4n + (((size_t)(s * 16 + segidx(s))) << 12);
    int4v A[2][4];
#pragma unroll
    for (int mi = 0; mi < 2; ++mi)
#pragma unroll
      for (int q = 0; q < 4; ++q)
        A[mi][q] = *reinterpret_cast<const int4v*>(abase + off[mi][q]);

#pragma unroll
    for (int nj = 0; nj < 2; ++nj) {
      f32x16 d0 = {};
      f32x16 d1 = {};
#pragma unroll
      for (int q = 0; q < 4; ++q) {
        frag_u a0, a1, bb;
        a0.i = A[0][q]; a1.i = A[1][q]; bb.i = B[q][nj];
        d0 = MFMA32(a0.v, bb.v, d0);
        d1 = MFMA32(a1.v, bb.v, d1);
      }
      // D -> B: 16 cvt_pk + 8 permlane32_swap per nj (pure VALU)
#pragma unroll
      for (int q = 0; q < 4; ++q) {
        const f32x16& dd = (q >> 1) ? d1 : d0;   // mi = q>>1 (compile-time)
        const int r0 = 8 * (q & 1);
        int pa0, pb0, pa1, pb1;
        asm("v_cvt_pk_bf16_f32 %0, %1, %2" : "=v"(pa0) : "v"(dd[r0]),     "v"(dd[r0 + 1]));
        asm("v_cvt_pk_bf16_f32 %0, %1, %2" : "=v"(pb0) : "v"(dd[r0 + 4]), "v"(dd[r0 + 5]));
        asm("v_cvt_pk_bf16_f32 %0, %1, %2" : "=v"(pa1) : "v"(dd[r0 + 2]), "v"(dd[r0 + 3]));
        asm("v_cvt_pk_bf16_f32 %0, %1, %2" : "=v"(pb1) : "v"(dd[r0 + 6]), "v"(dd[r0 + 7]));
        // after swap: pa = {Pa.lo31 | Pb.lo31} = word w ; pb = {Pa.hi31 | Pb.hi31} = word w+2
        asm("v_permlane32_swap_b32 %0, %1" : "+v"(pa0), "+v"(pb0));
        asm("v_permlane32_swap_b32 %0, %1" : "+v"(pa1), "+v"(pb1));
        int4v nb = { pa0, pa1, pb0, pb1 };
        B[q][nj] = nb;
      }
    }
  }

  // psi = tr(P4[0][idx0] * E): per-lane dot of A-frags with B-frags (no MFMA, no DS)
  float psum = 0.f;
  {
    const unsigned short* abase = P4n + (((size_t)segidx(0)) << 12);
#pragma unroll
    for (int mi = 0; mi < 2; ++mi)
#pragma unroll
      for (int q = 0; q < 4; ++q) {
        int4v av = *reinterpret_cast<const int4v*>(abase + off[mi][q]);
        int4v bv = B[q][mi];
#pragma unroll
        for (int w = 0; w < 4; ++w) {
          union { unsigned u; float f; } alo, ahi, blo, bhi;
          alo.u = ((unsigned)av[w]) << 16;
          ahi.u = ((unsigned)av[w]) & 0xFFFF0000u;
          blo.u = ((unsigned)bv[w]) << 16;
          bhi.u = ((unsigned)bv[w]) & 0xFFFF0000u;
          psum += alo.f * blo.f + ahi.f * bhi.f;
        }
      }
  }
#pragma unroll
  for (int o = 32; o > 0; o >>= 1) psum += __shfl_down(psum, o, 64);
  if (l == 0) out[b] = logf(fabsf(psum));
}

// ---------------- launch ----------------
extern "C" void kernel_launch(void* const* d_in, const int* in_sizes, int n_in,
                              void* d_out, int out_size, void* d_ws, size_t ws_size,
                              hipStream_t stream) {
  const int*   x     = (const int*)d_in[0];     // [4096][64] int32
  const float* param = (const float*)d_in[1];   // [64][2][64][64] f32
  float* out = (float*)d_out;                   // 4096 floats: log|psi_b|

  char* ws = (char*)d_ws;
  unsigned short* Tn  = (unsigned short*)(ws + (0ull << 20));   // 1 MB
  unsigned short* Tt  = (unsigned short*)(ws + (1ull << 20));   // 1 MB
  unsigned short* P4n = (unsigned short*)(ws + (2ull << 20));   // 2 MB (256 x 8 KB), L2-resident
  unsigned short* P4t = (unsigned short*)(ws + (4ull << 20));   // 128 KB (16 x 8 KB)

  prep_kernel<<<2048, 256, 0, stream>>>(param, Tn, Tt);
  build_p4_kernel<<<64, 256, 0, stream>>>(Tn, Tt, P4n, P4t);
  chain_wave32_kernel<<<1024, 256, 0, stream>>>(x, P4n, P4t, out);
}

// Round 16
// 56.131 us; speedup vs baseline: 1.4670x; 1.4041x over previous
//
#include <hip/hip_runtime.h>

// MPS periodic chain: psi_b = tr( prod_{i=0..63} (param[i][x[b,i]] + I) )
// d_out: float32[4096], out[b] = log|psi_b|.
//
// Round-15 lesson: chain was bound by LANE-DIVERGENT global loads (each frag
// load = 64 lanes x 16B at 128-B stride -> ~64 L2 sub-transactions). Fix:
// store P4 matrices PRE-SWIZZLED in fragment-linear layout so every chain
// load is base + (frag<<10) + (lane<<4) -- fully coalesced 1 KB/instruction.
//
//  prep:      T = param + I -> bf16 (Tn row-major, Tt transposed)  [unchanged]
//  build_p4:  256 waves (verified 16x16+bpermute path): P4[s][c] =
//             prod_{j=0..3} T[4s+j][bit]; final D scattered into:
//               Pa[s*16+c]: A-frag-linear (chain A-operands + final dot), all s
//               Pb[c]:      B-frag-linear (chain init), s==15 only
//  chain32:   one wave per batch (verified round-15 structure, only the
//             load addressing changed): E := Pb[i15]; for s=14..1:
//             E := Pa[s][is]*E (16 MFMA32 + 32 cvt_pk + 16 permlane32_swap,
//             zero DS); psi = per-lane dot with Pa[0][i0]; out = log|psi|.
//
// 32x32x16 layouts (verified r15): A: lane l holds X[m=l&31][k=8*(l>>5)+j];
// B: Y[k=8*(l>>5)+j][n=l&31]; D: C[row=(r&3)+8*(r>>2)+4*(l>>5)][col=l&31].
// Frag-linear addressing (64x64 matrix as 8 frags):
//  Pa: frag i=(mi*4+q) holds elem (32mi+c5, 16q+8*l5+j) at i*1024 + l*16 + 2j
//  Pb: frag i=(q*2+nj)  holds elem (16q+8*l5+j, 32nj+c5) at i*1024 + l*16 + 2j

typedef __attribute__((ext_vector_type(8)))  __bf16 bf16x8;
typedef __attribute__((ext_vector_type(4)))  float  f32x4;
typedef __attribute__((ext_vector_type(16))) float  f32x16;
typedef __attribute__((ext_vector_type(4)))  int    int4v;

#define MFMA16(a, b, c) __builtin_amdgcn_mfma_f32_16x16x32_bf16((a), (b), (c), 0, 0, 0)
#define MFMA32(a, b, c) __builtin_amdgcn_mfma_f32_32x32x16_bf16((a), (b), (c), 0, 0, 0)

union frag_u { int4v i; bf16x8 v; };

__device__ __forceinline__ unsigned short f2bf(float f) {
  union { float f; unsigned u; } v; v.f = f;
  unsigned r = v.u + 0x7fffu + ((v.u >> 16) & 1u);   // RNE
  return (unsigned short)(r >> 16);
}

// ---------------- phase 0: param + I -> bf16, normal + transposed ----------------
__global__ __launch_bounds__(256) void prep_kernel(const float* __restrict__ p,
                                                   unsigned short* __restrict__ Tn,
                                                   unsigned short* __restrict__ Tt) {
  int t = blockIdx.x * 256 + threadIdx.x;      // 0 .. 524287
  int j  = t & 63;
  int i  = (t >> 6) & 63;
  int pq = t >> 12;                            // [site][digit] 0..127
  float v = p[t] + ((i == j) ? 1.0f : 0.0f);
  unsigned short h = f2bf(v);
  Tn[t] = h;
  Tt[(((size_t)pq) << 12) + (size_t)j * 64 + i] = h;
}

// ---------------- phase 1: P4 table -> fragment-linear stores ----------------
__global__ __launch_bounds__(256) void build_p4_kernel(const unsigned short* __restrict__ Tn,
                                                       const unsigned short* __restrict__ Tt,
                                                       unsigned short* __restrict__ Pa,
                                                       unsigned short* __restrict__ Pb) {
  const int tid = threadIdx.x;
  const int l   = tid & 63;
  const int w   = blockIdx.x * 4 + (tid >> 6);   // 0..255
  const int s   = w >> 4, cmb = w & 15;          // segment (4 sites), combo (site 4s = MSB)
  const int c   = l & 15, p = l >> 4;

  const int srcA = (l & 15) | ((l & 16) << 1);
  const int srcB = srcA | 16;
  const bool hi5 = (l & 32) != 0;

  // B := T[site 4s+3] as 16x16 B-frags from Tt (verified path)
  frag_u B[2][4];
  {
    int m3 = (4 * s + 3) * 2 + (cmb & 1);
    const unsigned short* base = Tt + ((size_t)m3 << 12);
#pragma unroll
    for (int ks = 0; ks < 2; ++ks)
#pragma unroll
      for (int nj = 0; nj < 4; ++nj)
        B[ks][nj].i = *reinterpret_cast<const int4v*>(base + (c + 16 * nj) * 64 + 32 * ks + 8 * p);
  }

#pragma unroll
  for (int j = 2; j >= 1; --j) {
    int m = (4 * s + j) * 2 + ((cmb >> (3 - j)) & 1);
    const unsigned short* abase = Tn + ((size_t)m << 12);
    frag_u A[4][2];
#pragma unroll
    for (int mi = 0; mi < 4; ++mi)
#pragma unroll
      for (int ks = 0; ks < 2; ++ks)
        A[mi][ks].i = *reinterpret_cast<const int4v*>(abase + (c + 16 * mi) * 64 + 32 * ks + 8 * p);

    int pk[4][4][2];
#pragma unroll
    for (int mi = 0; mi < 4; ++mi)
#pragma unroll
      for (int nj = 0; nj < 4; ++nj) {
        f32x4 d = {0.f, 0.f, 0.f, 0.f};
        d = MFMA16(A[mi][0].v, B[0][nj].v, d);
        d = MFMA16(A[mi][1].v, B[1][nj].v, d);
        asm("v_cvt_pk_bf16_f32 %0, %1, %2" : "=v"(pk[mi][nj][0]) : "v"(d[0]), "v"(d[1]));
        asm("v_cvt_pk_bf16_f32 %0, %1, %2" : "=v"(pk[mi][nj][1]) : "v"(d[2]), "v"(d[3]));
      }
#pragma unroll
    for (int ks = 0; ks < 2; ++ks)
#pragma unroll
      for (int nj = 0; nj < 4; ++nj) {
        int lo0 = pk[2 * ks][nj][0],     lo1 = pk[2 * ks][nj][1];
        int hi0 = pk[2 * ks + 1][nj][0], hi1 = pk[2 * ks + 1][nj][1];
        int a0 = __shfl(lo0, srcA, 64), b0 = __shfl(hi0, srcA, 64);
        int a1 = __shfl(lo1, srcA, 64), b1 = __shfl(hi1, srcA, 64);
        int a2 = __shfl(lo0, srcB, 64), b2 = __shfl(hi0, srcB, 64);
        int a3 = __shfl(lo1, srcB, 64), b3 = __shfl(hi1, srcB, 64);
        int4v nb = { hi5 ? b0 : a0, hi5 ? b1 : a1, hi5 ? b2 : a2, hi5 ? b3 : a3 };
        B[ks][nj].i = nb;
      }
  }

  // final site 4s: D = A(T) x B; scatter into fragment-linear Pa (+Pb for s==15)
  {
    int m0 = (4 * s) * 2 + ((cmb >> 3) & 1);
    const unsigned short* abase = Tn + ((size_t)m0 << 12);
    frag_u A[4][2];
#pragma unroll
    for (int mi = 0; mi < 4; ++mi)
#pragma unroll
      for (int ks = 0; ks < 2; ++ks)
        A[mi][ks].i = *reinterpret_cast<const int4v*>(abase + (c + 16 * mi) * 64 + 32 * ks + 8 * p);

    unsigned short* PAv = Pa + (((size_t)w) << 12);
    unsigned short* PBv = Pb + (((size_t)cmb) << 12);
    const bool wantB = (s == 15);
#pragma unroll
    for (int mi16 = 0; mi16 < 4; ++mi16)
#pragma unroll
      for (int nj16 = 0; nj16 < 4; ++nj16) {
        f32x4 d = {0.f, 0.f, 0.f, 0.f};
        d = MFMA16(A[mi16][0].v, B[0][nj16].v, d);
        d = MFMA16(A[mi16][1].v, B[1][nj16].v, d);
#pragma unroll
        for (int r = 0; r < 4; ++r) {
          int row = 16 * mi16 + 4 * p + r, col = 16 * nj16 + c;
          unsigned short v = f2bf(d[r]);
          // Pa: frag i=(row>>5)*4 + ((col>>4)&3); lane=((col>>3)&1)*32+(row&31); j=col&7
          int ia = ((row >> 5) << 2) | ((col >> 4) & 3);
          int la = (((col >> 3) & 1) << 5) | (row & 31);
          PAv[ia * 512 + la * 8 + (col & 7)] = v;
          if (wantB) {
            // Pb: frag i=((row>>4)&3)*2 + (col>>5); lane=((row>>3)&1)*32+(col&31); j=row&7
            int ib = (((row >> 4) & 3) << 1) | (col >> 5);
            int lb2 = (((row >> 3) & 1) << 5) | (col & 31);
            PBv[ib * 512 + lb2 * 8 + (row & 7)] = v;
          }
        }
      }
  }
}

// ---------------- phase 2: 32x32 register chain, coalesced frag-linear loads ----------------
__global__ __launch_bounds__(256) void chain_wave32_kernel(const int* __restrict__ x,
                                                           const unsigned short* __restrict__ Pa,
                                                           const unsigned short* __restrict__ Pb,
                                                           float* __restrict__ out) {
  const int tid = threadIdx.x;
  const int l   = tid & 63;
  const int b   = blockIdx.x * 4 + (tid >> 6);   // one wave per batch
  const int lb  = l << 4;                        // this lane's byte offset in a 1KB frag

  // wave-uniform bit mask of this batch's digits
  unsigned long long mask = __ballot((x[b * 64 + l] & 1) != 0);

  // segment index from the 4-bit nibble (leftmost site = MSB)
  auto segidx = [&](int s) -> int {
    unsigned nib = (unsigned)((mask >> (4 * s)) & 0xFull);
    return (int)(((nib & 1u) << 3) | ((nib & 2u) << 1) | ((nib & 4u) >> 1) | ((nib & 8u) >> 3));
  };

  // E := P4[15][idx15] as B-frags (coalesced from Pb)
  int4v B[4][2];
  {
    const char* base = (const char*)(Pb + (((size_t)segidx(15)) << 12));
#pragma unroll
    for (int q = 0; q < 4; ++q)
#pragma unroll
      for (int nj = 0; nj < 2; ++nj)
        B[q][nj] = *reinterpret_cast<const int4v*>(base + (((q << 1) | nj) << 10) + lb);
  }

  // steps s = 14..1 : E := P4[s][idx_s] * E   (coalesced L2-resident A reads)
#pragma unroll 1
  for (int s = 14; s >= 1; --s) {
    const char* abase = (const char*)(Pa + (((size_t)(s * 16 + segidx(s))) << 12));
    int4v A[2][4];
#pragma unroll
    for (int mi = 0; mi < 2; ++mi)
#pragma unroll
      for (int q = 0; q < 4; ++q)
        A[mi][q] = *reinterpret_cast<const int4v*>(abase + (((mi << 2) | q) << 10) + lb);

#pragma unroll
    for (int nj = 0; nj < 2; ++nj) {
      f32x16 d0 = {};
      f32x16 d1 = {};
#pragma unroll
      for (int q = 0; q < 4; ++q) {
        frag_u a0, a1, bb;
        a0.i = A[0][q]; a1.i = A[1][q]; bb.i = B[q][nj];
        d0 = MFMA32(a0.v, bb.v, d0);
        d1 = MFMA32(a1.v, bb.v, d1);
      }
      // D -> B: 16 cvt_pk + 8 permlane32_swap per nj (pure VALU, verified r15)
#pragma unroll
      for (int q = 0; q < 4; ++q) {
        const f32x16& dd = (q >> 1) ? d1 : d0;   // mi = q>>1 (compile-time)
        const int r0 = 8 * (q & 1);
        int pa0, pb0, pa1, pb1;
        asm("v_cvt_pk_bf16_f32 %0, %1, %2" : "=v"(pa0) : "v"(dd[r0]),     "v"(dd[r0 + 1]));
        asm("v_cvt_pk_bf16_f32 %0, %1, %2" : "=v"(pb0) : "v"(dd[r0 + 4]), "v"(dd[r0 + 5]));
        asm("v_cvt_pk_bf16_f32 %0, %1, %2" : "=v"(pa1) : "v"(dd[r0 + 2]), "v"(dd[r0 + 3]));
        asm("v_cvt_pk_bf16_f32 %0, %1, %2" : "=v"(pb1) : "v"(dd[r0 + 6]), "v"(dd[r0 + 7]));
        asm("v_permlane32_swap_b32 %0, %1" : "+v"(pa0), "+v"(pb0));
        asm("v_permlane32_swap_b32 %0, %1" : "+v"(pa1), "+v"(pb1));
        int4v nb = { pa0, pa1, pb0, pb1 };
        B[q][nj] = nb;
      }
    }
  }

  // psi = tr(P4[0][idx0] * E): per-lane dot of A-frags with B-frags (verified r15)
  float psum = 0.f;
  {
    const char* abase = (const char*)(Pa + (((size_t)segidx(0)) << 12));
#pragma unroll
    for (int mi = 0; mi < 2; ++mi)
#pragma unroll
      for (int q = 0; q < 4; ++q) {
        int4v av = *reinterpret_cast<const int4v*>(abase + (((mi << 2) | q) << 10) + lb);
        int4v bv = B[q][mi];
#pragma unroll
        for (int w = 0; w < 4; ++w) {
          union { unsigned u; float f; } alo, ahi, blo, bhi;
          alo.u = ((unsigned)av[w]) << 16;
          ahi.u = ((unsigned)av[w]) & 0xFFFF0000u;
          blo.u = ((unsigned)bv[w]) << 16;
          bhi.u = ((unsigned)bv[w]) & 0xFFFF0000u;
          psum += alo.f * blo.f + ahi.f * bhi.f;
        }
      }
  }
#pragma unroll
  for (int o = 32; o > 0; o >>= 1) psum += __shfl_down(psum, o, 64);
  if (l == 0) out[b] = logf(fabsf(psum));
}

// ---------------- launch ----------------
extern "C" void kernel_launch(void* const* d_in, const int* in_sizes, int n_in,
                              void* d_out, int out_size, void* d_ws, size_t ws_size,
                              hipStream_t stream) {
  const int*   x     = (const int*)d_in[0];     // [4096][64] int32
  const float* param = (const float*)d_in[1];   // [64][2][64][64] f32
  float* out = (float*)d_out;                   // 4096 floats: log|psi_b|

  char* ws = (char*)d_ws;
  unsigned short* Tn = (unsigned short*)(ws + (0ull << 20));   // 1 MB
  unsigned short* Tt = (unsigned short*)(ws + (1ull << 20));   // 1 MB
  unsigned short* Pa = (unsigned short*)(ws + (2ull << 20));   // 2 MB: 256 x 8 KB, A-frag-linear
  unsigned short* Pb = (unsigned short*)(ws + (4ull << 20));   // 128 KB: 16 x 8 KB, B-frag-linear

  prep_kernel<<<2048, 256, 0, stream>>>(param, Tn, Tt);
  build_p4_kernel<<<64, 256, 0, stream>>>(Tn, Tt, Pa, Pb);
  chain_wave32_kernel<<<1024, 256, 0, stream>>>(x, Pa, Pb, out);
}

// Round 17
// 54.403 us; speedup vs baseline: 1.5136x; 1.0318x over previous
//
#include <hip/hip_runtime.h>

// MPS periodic chain: psi_b = tr( prod_{i=0..63} (param[i][x[b,i]] + I) )
// d_out: float32[4096], out[b] = log|psi_b|.
//
// Round-16 lesson: coalesced frag-linear loads fixed the scatter (67->39.6us),
// but the chain is still latency-bound (MfmaUtil 28%, VALU 37%, occ 21%):
// with unroll-1, each step's A-loads stall ~200+cyc L2 latency on the loop
// back-edge. Fix: manual 2x-unrolled ping-pong A prefetch (A0/A1 named bufs,
// rule #20) -- next step's 8 loads issue between the two nj-halves of the
// current step's MFMA+convert, hiding L2 latency under ~300cyc of compute.
// Bonus: prefetch of step s=1 loads segment 0 = exactly the final dot's A-frags.
//
//  prep:      T = param + I -> bf16 (Tn row-major, Tt transposed)  [unchanged]
//  build_p4:  256 waves (verified): P4[s][c] -> Pa frag-linear (all s),
//             Pb frag-linear (s==15)                              [unchanged]
//  chain32:   one wave per batch: E := Pb[i15]; 14x E := Pa[s][is]*E
//             (16 MFMA32 + 32 cvt_pk + 16 permlane32_swap, zero DS, pipelined
//             A-prefetch); psi = per-lane dot with prefetched seg-0 A-frags.
//
// 32x32x16 layouts (verified r15/r16): A: lane l holds X[m=l&31][k=8*(l>>5)+j];
// B: Y[k=8*(l>>5)+j][n=l&31]; D: C[row=(r&3)+8*(r>>2)+4*(l>>5)][col=l&31].
// Frag-linear: Pa frag i=(mi*4+q) elem (32mi+c5, 16q+8*l5+j) at i*1024+l*16+2j;
//              Pb frag i=(q*2+nj)  elem (16q+8*l5+j, 32nj+c5) at i*1024+l*16+2j.

typedef __attribute__((ext_vector_type(8)))  __bf16 bf16x8;
typedef __attribute__((ext_vector_type(4)))  float  f32x4;
typedef __attribute__((ext_vector_type(16))) float  f32x16;
typedef __attribute__((ext_vector_type(4)))  int    int4v;

#define MFMA16(a, b, c) __builtin_amdgcn_mfma_f32_16x16x32_bf16((a), (b), (c), 0, 0, 0)
#define MFMA32(a, b, c) __builtin_amdgcn_mfma_f32_32x32x16_bf16((a), (b), (c), 0, 0, 0)

union frag_u { int4v i; bf16x8 v; };

__device__ __forceinline__ unsigned short f2bf(float f) {
  union { float f; unsigned u; } v; v.f = f;
  unsigned r = v.u + 0x7fffu + ((v.u >> 16) & 1u);   // RNE
  return (unsigned short)(r >> 16);
}

// ---------------- phase 0: param + I -> bf16, normal + transposed ----------------
__global__ __launch_bounds__(256) void prep_kernel(const float* __restrict__ p,
                                                   unsigned short* __restrict__ Tn,
                                                   unsigned short* __restrict__ Tt) {
  int t = blockIdx.x * 256 + threadIdx.x;      // 0 .. 524287
  int j  = t & 63;
  int i  = (t >> 6) & 63;
  int pq = t >> 12;                            // [site][digit] 0..127
  float v = p[t] + ((i == j) ? 1.0f : 0.0f);
  unsigned short h = f2bf(v);
  Tn[t] = h;
  Tt[(((size_t)pq) << 12) + (size_t)j * 64 + i] = h;
}

// ---------------- phase 1: P4 table -> fragment-linear stores (verified r16) ----------------
__global__ __launch_bounds__(256) void build_p4_kernel(const unsigned short* __restrict__ Tn,
                                                       const unsigned short* __restrict__ Tt,
                                                       unsigned short* __restrict__ Pa,
                                                       unsigned short* __restrict__ Pb) {
  const int tid = threadIdx.x;
  const int l   = tid & 63;
  const int w   = blockIdx.x * 4 + (tid >> 6);   // 0..255
  const int s   = w >> 4, cmb = w & 15;          // segment (4 sites), combo (site 4s = MSB)
  const int c   = l & 15, p = l >> 4;

  const int srcA = (l & 15) | ((l & 16) << 1);
  const int srcB = srcA | 16;
  const bool hi5 = (l & 32) != 0;

  frag_u B[2][4];
  {
    int m3 = (4 * s + 3) * 2 + (cmb & 1);
    const unsigned short* base = Tt + ((size_t)m3 << 12);
#pragma unroll
    for (int ks = 0; ks < 2; ++ks)
#pragma unroll
      for (int nj = 0; nj < 4; ++nj)
        B[ks][nj].i = *reinterpret_cast<const int4v*>(base + (c + 16 * nj) * 64 + 32 * ks + 8 * p);
  }

#pragma unroll
  for (int j = 2; j >= 1; --j) {
    int m = (4 * s + j) * 2 + ((cmb >> (3 - j)) & 1);
    const unsigned short* abase = Tn + ((size_t)m << 12);
    frag_u A[4][2];
#pragma unroll
    for (int mi = 0; mi < 4; ++mi)
#pragma unroll
      for (int ks = 0; ks < 2; ++ks)
        A[mi][ks].i = *reinterpret_cast<const int4v*>(abase + (c + 16 * mi) * 64 + 32 * ks + 8 * p);

    int pk[4][4][2];
#pragma unroll
    for (int mi = 0; mi < 4; ++mi)
#pragma unroll
      for (int nj = 0; nj < 4; ++nj) {
        f32x4 d = {0.f, 0.f, 0.f, 0.f};
        d = MFMA16(A[mi][0].v, B[0][nj].v, d);
        d = MFMA16(A[mi][1].v, B[1][nj].v, d);
        asm("v_cvt_pk_bf16_f32 %0, %1, %2" : "=v"(pk[mi][nj][0]) : "v"(d[0]), "v"(d[1]));
        asm("v_cvt_pk_bf16_f32 %0, %1, %2" : "=v"(pk[mi][nj][1]) : "v"(d[2]), "v"(d[3]));
      }
#pragma unroll
    for (int ks = 0; ks < 2; ++ks)
#pragma unroll
      for (int nj = 0; nj < 4; ++nj) {
        int lo0 = pk[2 * ks][nj][0],     lo1 = pk[2 * ks][nj][1];
        int hi0 = pk[2 * ks + 1][nj][0], hi1 = pk[2 * ks + 1][nj][1];
        int a0 = __shfl(lo0, srcA, 64), b0 = __shfl(hi0, srcA, 64);
        int a1 = __shfl(lo1, srcA, 64), b1 = __shfl(hi1, srcA, 64);
        int a2 = __shfl(lo0, srcB, 64), b2 = __shfl(hi0, srcB, 64);
        int a3 = __shfl(lo1, srcB, 64), b3 = __shfl(hi1, srcB, 64);
        int4v nb = { hi5 ? b0 : a0, hi5 ? b1 : a1, hi5 ? b2 : a2, hi5 ? b3 : a3 };
        B[ks][nj].i = nb;
      }
  }

  {
    int m0 = (4 * s) * 2 + ((cmb >> 3) & 1);
    const unsigned short* abase = Tn + ((size_t)m0 << 12);
    frag_u A[4][2];
#pragma unroll
    for (int mi = 0; mi < 4; ++mi)
#pragma unroll
      for (int ks = 0; ks < 2; ++ks)
        A[mi][ks].i = *reinterpret_cast<const int4v*>(abase + (c + 16 * mi) * 64 + 32 * ks + 8 * p);

    unsigned short* PAv = Pa + (((size_t)w) << 12);
    unsigned short* PBv = Pb + (((size_t)cmb) << 12);
    const bool wantB = (s == 15);
#pragma unroll
    for (int mi16 = 0; mi16 < 4; ++mi16)
#pragma unroll
      for (int nj16 = 0; nj16 < 4; ++nj16) {
        f32x4 d = {0.f, 0.f, 0.f, 0.f};
        d = MFMA16(A[mi16][0].v, B[0][nj16].v, d);
        d = MFMA16(A[mi16][1].v, B[1][nj16].v, d);
#pragma unroll
        for (int r = 0; r < 4; ++r) {
          int row = 16 * mi16 + 4 * p + r, col = 16 * nj16 + c;
          unsigned short v = f2bf(d[r]);
          int ia = ((row >> 5) << 2) | ((col >> 4) & 3);
          int la = (((col >> 3) & 1) << 5) | (row & 31);
          PAv[ia * 512 + la * 8 + (col & 7)] = v;
          if (wantB) {
            int ib = (((row >> 4) & 3) << 1) | (col >> 5);
            int lb2 = (((row >> 3) & 1) << 5) | (col & 31);
            PBv[ib * 512 + lb2 * 8 + (row & 7)] = v;
          }
        }
      }
  }
}

// ---------------- chain helpers ----------------
__device__ __forceinline__ void load_afrags(const char* abase, int lb, int4v (&A)[2][4]) {
#pragma unroll
  for (int mi = 0; mi < 2; ++mi)
#pragma unroll
    for (int q = 0; q < 4; ++q)
      A[mi][q] = *reinterpret_cast<const int4v*>(abase + (((mi << 2) | q) << 10) + lb);
}

// one nj-half of a chain step: 8 MFMA32 accumulate + D->B convert (verified r15/r16)
__device__ __forceinline__ void mm_convert_nj(const int4v (&Ac)[2][4], int4v (&B)[4][2], int nj) {
  f32x16 d0 = {};
  f32x16 d1 = {};
#pragma unroll
  for (int q = 0; q < 4; ++q) {
    frag_u a0, a1, bb;
    a0.i = Ac[0][q]; a1.i = Ac[1][q]; bb.i = B[q][nj];
    d0 = MFMA32(a0.v, bb.v, d0);
    d1 = MFMA32(a1.v, bb.v, d1);
  }
#pragma unroll
  for (int q = 0; q < 4; ++q) {
    const f32x16& dd = (q >> 1) ? d1 : d0;   // mi = q>>1 (compile-time)
    const int r0 = 8 * (q & 1);
    int pa0, pb0, pa1, pb1;
    asm("v_cvt_pk_bf16_f32 %0, %1, %2" : "=v"(pa0) : "v"(dd[r0]),     "v"(dd[r0 + 1]));
    asm("v_cvt_pk_bf16_f32 %0, %1, %2" : "=v"(pb0) : "v"(dd[r0 + 4]), "v"(dd[r0 + 5]));
    asm("v_cvt_pk_bf16_f32 %0, %1, %2" : "=v"(pa1) : "v"(dd[r0 + 2]), "v"(dd[r0 + 3]));
    asm("v_cvt_pk_bf16_f32 %0, %1, %2" : "=v"(pb1) : "v"(dd[r0 + 6]), "v"(dd[r0 + 7]));
    asm("v_permlane32_swap_b32 %0, %1" : "+v"(pa0), "+v"(pb0));
    asm("v_permlane32_swap_b32 %0, %1" : "+v"(pa1), "+v"(pb1));
    int4v nb = { pa0, pa1, pb0, pb1 };
    B[q][nj] = nb;
  }
}

// ---------------- phase 2: pipelined 32x32 register chain ----------------
__global__ __launch_bounds__(256) void chain_wave32_kernel(const int* __restrict__ x,
                                                           const unsigned short* __restrict__ Pa,
                                                           const unsigned short* __restrict__ Pb,
                                                           float* __restrict__ out) {
  const int tid = threadIdx.x;
  const int l   = tid & 63;
  const int b   = blockIdx.x * 4 + (tid >> 6);   // one wave per batch
  const int lb  = l << 4;                        // lane's byte offset in a 1KB frag

  unsigned long long mask = __ballot((x[b * 64 + l] & 1) != 0);

  auto segidx = [&](int s) -> int {
    unsigned nib = (unsigned)((mask >> (4 * s)) & 0xFull);
    return (int)(((nib & 1u) << 3) | ((nib & 2u) << 1) | ((nib & 4u) >> 1) | ((nib & 8u) >> 3));
  };
  auto aaddr = [&](int s) -> const char* {
    return (const char*)(Pa + (((size_t)(s * 16 + segidx(s))) << 12));
  };

  // E := P4[15][idx15] as B-frags (coalesced from Pb)
  int4v B[4][2];
  {
    const char* base = (const char*)(Pb + (((size_t)segidx(15)) << 12));
#pragma unroll
    for (int q = 0; q < 4; ++q)
#pragma unroll
      for (int nj = 0; nj < 2; ++nj)
        B[q][nj] = *reinterpret_cast<const int4v*>(base + (((q << 1) | nj) << 10) + lb);
  }

  // 14 steps s=14..1, 2x unrolled with ping-pong A0/A1 prefetch.
  // Prefetch of step s loads segment s-1; the t=6 tail loads segment 0,
  // which is exactly the final trace-dot's A operand.
  int4v A0[2][4], A1[2][4];
  load_afrags(aaddr(14), lb, A0);
#pragma unroll
  for (int t = 0; t < 7; ++t) {
    const int s = 14 - 2 * t;
    // step s (A0): nj=0 half, then issue prefetch, then nj=1 half
    mm_convert_nj(A0, B, 0);
    load_afrags(aaddr(s - 1), lb, A1);
    mm_convert_nj(A0, B, 1);
    // step s-1 (A1): same pattern, prefetch s-2 into A0
    mm_convert_nj(A1, B, 0);
    load_afrags(aaddr(s - 2), lb, A0);
    mm_convert_nj(A1, B, 1);
  }

  // psi = tr(P4[0][idx0] * E): per-lane dot; A0 holds segment-0 A-frags
  float psum = 0.f;
#pragma unroll
  for (int mi = 0; mi < 2; ++mi)
#pragma unroll
    for (int q = 0; q < 4; ++q) {
      int4v av = A0[mi][q];
      int4v bv = B[q][mi];
#pragma unroll
      for (int w = 0; w < 4; ++w) {
        union { unsigned u; float f; } alo, ahi, blo, bhi;
        alo.u = ((unsigned)av[w]) << 16;
        ahi.u = ((unsigned)av[w]) & 0xFFFF0000u;
        blo.u = ((unsigned)bv[w]) << 16;
        bhi.u = ((unsigned)bv[w]) & 0xFFFF0000u;
        psum += alo.f * blo.f + ahi.f * bhi.f;
      }
    }
#pragma unroll
  for (int o = 32; o > 0; o >>= 1) psum += __shfl_down(psum, o, 64);
  if (l == 0) out[b] = logf(fabsf(psum));
}

// ---------------- launch ----------------
extern "C" void kernel_launch(void* const* d_in, const int* in_sizes, int n_in,
                              void* d_out, int out_size, void* d_ws, size_t ws_size,
                              hipStream_t stream) {
  const int*   x     = (const int*)d_in[0];     // [4096][64] int32
  const float* param = (const float*)d_in[1];   // [64][2][64][64] f32
  float* out = (float*)d_out;                   // 4096 floats: log|psi_b|

  char* ws = (char*)d_ws;
  unsigned short* Tn = (unsigned short*)(ws + (0ull << 20));   // 1 MB
  unsigned short* Tt = (unsigned short*)(ws + (1ull << 20));   // 1 MB
  unsigned short* Pa = (unsigned short*)(ws + (2ull << 20));   // 2 MB: 256 x 8 KB, A-frag-linear
  unsigned short* Pb = (unsigned short*)(ws + (4ull << 20));   // 128 KB: 16 x 8 KB, B-frag-linear

  prep_kernel<<<2048, 256, 0, stream>>>(param, Tn, Tt);
  build_p4_kernel<<<64, 256, 0, stream>>>(Tn, Tt, Pa, Pb);
  chain_wave32_kernel<<<1024, 256, 0, stream>>>(x, Pa, Pb, out);
}